// Round 3
// baseline (280.368 us; speedup 1.0000x reference)
//
#include <hip/hip_runtime.h>
#include <cstddef>

#define HW 16384

typedef short s8v __attribute__((ext_vector_type(8)));
typedef short s4v __attribute__((ext_vector_type(4)));
typedef float f4v __attribute__((ext_vector_type(4)));

__device__ inline short f2b(float x) {
    union { float f; unsigned u; } v; v.f = x;
    unsigned r = v.u + 0x7fff + ((v.u >> 16) & 1);
    return (short)(r >> 16);
}
__device__ inline float b2f(short h) {
    union { unsigned u; float f; } v;
    v.u = ((unsigned)(unsigned short)h) << 16;
    return v.f;
}
__device__ inline void gload_lds16(const void* gsrc, void* ldst) {
    __builtin_amdgcn_global_load_lds(
        (const __attribute__((address_space(1))) unsigned int*)gsrc,
        (__attribute__((address_space(3))) unsigned int*)ldst, 16, 0, 0);
}

// ---------------- k_prep_w: weights -> chunk-tiled bf16 hi/lo ----------------
// Wthi[c][512][32] (w1 rows 0..255, wv rows 256..511); Wtlo[c][256][32] (w1 only)
// w2thi/w2tlo[c][64][32]
__global__ __launch_bounds__(256) void k_prep_w(
    const float* __restrict__ w1, const float* __restrict__ wv,
    const float* __restrict__ w2,
    short* __restrict__ Wthi, short* __restrict__ Wtlo,
    short* __restrict__ w2thi, short* __restrict__ w2tlo)
{
    int tid = blockIdx.x * 256 + threadIdx.x;   // 0..147455
    if (tid < 131072) {
        int c = tid >> 14, r = tid & 16383, ch = r >> 5, kk = r & 31;
        float f = (ch < 256) ? w1[ch * 256 + c * 32 + kk]
                             : wv[(ch - 256) * 256 + c * 32 + kk];
        short hi = f2b(f);
        Wthi[tid] = hi;
        if (ch < 256) Wtlo[(c * 256 + ch) * 32 + kk] = f2b(f - b2f(hi));
    } else {
        int o = tid - 131072;                   // 0..16383
        int c = o >> 11, r = o & 2047, dir = r >> 5, kk = r & 31;
        float f = w2[dir * 256 + c * 32 + kk];
        short hi = f2b(f);
        w2thi[o] = hi;
        w2tlo[o] = f2b(f - b2f(hi));
    }
}

// ---------------- k_prep_u: u fp32 [b][ch][px] -> tiled bf16 hi/lo [b][c][px][32] --------
__global__ __launch_bounds__(256) void k_prep_u(
    const float* __restrict__ u, short* __restrict__ uthi, short* __restrict__ utlo)
{
    __shared__ __attribute__((aligned(16))) short shi[32 * 264];
    __shared__ __attribute__((aligned(16))) short slo[32 * 264];
    const int t = threadIdx.x;
    const int px_t = blockIdx.x;   // 0..63 -> p0 = px_t*256
    const int c    = blockIdx.y;   // 0..7
    const int b    = blockIdx.z;   // 0..3
    const float* ub = u + ((size_t)b * 256 + c * 32) * HW + px_t * 256;
    const int lane_px = (t & 63) * 4;
    const int chb = t >> 6;        // 0..3

    #pragma unroll
    for (int it = 0; it < 8; ++it) {
        int ch = it * 4 + chb;
        float4 v = *reinterpret_cast<const float4*>(ub + (size_t)ch * HW + lane_px);
        short h0 = f2b(v.x), h1 = f2b(v.y), h2 = f2b(v.z), h3 = f2b(v.w);
        s4v hv = {h0, h1, h2, h3};
        s4v lv = {f2b(v.x - b2f(h0)), f2b(v.y - b2f(h1)),
                  f2b(v.z - b2f(h2)), f2b(v.w - b2f(h3))};
        *reinterpret_cast<s4v*>(&shi[ch * 264 + lane_px]) = hv;
        *reinterpret_cast<s4v*>(&slo[ch * 264 + lane_px]) = lv;
    }
    __syncthreads();
    // phase 2: thread t -> pixel t of this 256-px tile
    union { short s[32]; s8v v[4]; } Uh, Ul;
    #pragma unroll
    for (int ch = 0; ch < 32; ++ch) {
        Uh.s[ch] = shi[ch * 264 + t];
        Ul.s[ch] = slo[ch * 264 + t];
    }
    size_t base = (((size_t)b * 8 + c) * 16384 + (size_t)px_t * 256 + t) * 32;
    #pragma unroll
    for (int g = 0; g < 4; ++g) {
        *reinterpret_cast<s8v*>(uthi + base + g * 8) = Uh.v[g];
        *reinterpret_cast<s8v*>(utlo + base + g * 8) = Ul.v[g];
    }
}

// ---------------- k_gemm1h: h = relu(w1 @ u + b1), split bf16 (3 MFMA) --------
// M=128 px, N=128 ch (blockIdx.y in {0,1}); h -> bf16 hi/lo pixel-major in d_out
__global__ __launch_bounds__(256) void k_gemm1h(
    const short* __restrict__ uthi, const short* __restrict__ utlo,
    const short* __restrict__ Wthi, const short* __restrict__ Wtlo,
    const float* __restrict__ b1,
    unsigned short* __restrict__ hhi, unsigned short* __restrict__ hlo)
{
    __shared__ __attribute__((aligned(16))) short Ah[128 * 32];
    __shared__ __attribute__((aligned(16))) short Al[128 * 32];
    __shared__ __attribute__((aligned(16))) short Bh[128 * 32];
    __shared__ __attribute__((aligned(16))) short Bl[128 * 32];

    const int t = threadIdx.x, l = t & 63, w = t >> 6;
    const int pt = blockIdx.x * 128;
    const int b = pt >> 14, p0 = pt & 16383;
    const int cbase = blockIdx.y * 128;

    f4v acc[4][4];
    #pragma unroll
    for (int i = 0; i < 4; ++i)
        #pragma unroll
        for (int j = 0; j < 4; ++j) acc[i][j] = (f4v){0.f, 0.f, 0.f, 0.f};

    const int m0 = (w >> 1) * 64, n0 = (w & 1) * 64;
    const int lr = l & 15, koff = (l >> 4) * 8;
    const size_t atile = (size_t)b * 4194304 + (size_t)p0 * 32;

    for (int c = 0; c < 8; ++c) {
        __syncthreads();
        const char* ah_src = (const char*)(uthi + atile + (size_t)c * 524288);
        const char* al_src = (const char*)(utlo + atile + (size_t)c * 524288);
        const char* bh_src = (const char*)(Wthi + (c * 512 + cbase) * 32);
        const char* bl_src = (const char*)(Wtlo + (c * 256 + cbase) * 32);
        #pragma unroll
        for (int it = 0; it < 2; ++it) {
            int off = (it * 4 + w) * 1024;
            gload_lds16(ah_src + off + l * 16, (char*)Ah + off);
            gload_lds16(al_src + off + l * 16, (char*)Al + off);
            gload_lds16(bh_src + off + l * 16, (char*)Bh + off);
            gload_lds16(bl_src + off + l * 16, (char*)Bl + off);
        }
        __syncthreads();

        s8v ah[4], al4[4], bh[4], bl4[4];
        #pragma unroll
        for (int i = 0; i < 4; ++i) {
            ah[i]  = *reinterpret_cast<const s8v*>(&Ah[(m0 + i * 16 + lr) * 32 + koff]);
            al4[i] = *reinterpret_cast<const s8v*>(&Al[(m0 + i * 16 + lr) * 32 + koff]);
        }
        #pragma unroll
        for (int j = 0; j < 4; ++j) {
            bh[j]  = *reinterpret_cast<const s8v*>(&Bh[(n0 + j * 16 + lr) * 32 + koff]);
            bl4[j] = *reinterpret_cast<const s8v*>(&Bl[(n0 + j * 16 + lr) * 32 + koff]);
        }
        #pragma unroll
        for (int i = 0; i < 4; ++i)
            #pragma unroll
            for (int j = 0; j < 4; ++j) {
                acc[i][j] = __builtin_amdgcn_mfma_f32_16x16x32_bf16(ah[i],  bh[j],  acc[i][j], 0, 0, 0);
                acc[i][j] = __builtin_amdgcn_mfma_f32_16x16x32_bf16(ah[i],  bl4[j], acc[i][j], 0, 0, 0);
                acc[i][j] = __builtin_amdgcn_mfma_f32_16x16x32_bf16(al4[i], bh[j],  acc[i][j], 0, 0, 0);
            }
    }

    const int quad = l >> 4;
    #pragma unroll
    for (int j = 0; j < 4; ++j) {
        int ch = cbase + n0 + j * 16 + lr;
        float bias = b1[ch];
        #pragma unroll
        for (int i = 0; i < 4; ++i)
            #pragma unroll
            for (int r = 0; r < 4; ++r) {
                int m = m0 + i * 16 + quad * 4 + r;
                size_t pix = (size_t)(b << 14) + p0 + m;
                float v = fmaxf(acc[i][j][r] + bias, 0.f);
                short hi = f2b(v);
                hhi[pix * 256 + ch] = (unsigned short)hi;
                hlo[pix * 256 + ch] = (unsigned short)f2b(v - b2f(hi));
            }
    }
}

// ---------------- k_gemm1v: value = wv @ u + bv, plain bf16 -> vbuf ----------
__global__ __launch_bounds__(256) void k_gemm1v(
    const short* __restrict__ uthi, const short* __restrict__ Wthi,
    const float* __restrict__ bv, unsigned short* __restrict__ vbuf)
{
    __shared__ __attribute__((aligned(16))) short Ah[128 * 32];
    __shared__ __attribute__((aligned(16))) short Bh[128 * 32];

    const int t = threadIdx.x, l = t & 63, w = t >> 6;
    const int pt = blockIdx.x * 128;
    const int b = pt >> 14, p0 = pt & 16383;
    const int cbase = 256 + blockIdx.y * 128;

    f4v acc[4][4];
    #pragma unroll
    for (int i = 0; i < 4; ++i)
        #pragma unroll
        for (int j = 0; j < 4; ++j) acc[i][j] = (f4v){0.f, 0.f, 0.f, 0.f};

    const int m0 = (w >> 1) * 64, n0 = (w & 1) * 64;
    const int lr = l & 15, koff = (l >> 4) * 8;
    const size_t atile = (size_t)b * 4194304 + (size_t)p0 * 32;

    for (int c = 0; c < 8; ++c) {
        __syncthreads();
        const char* ah_src = (const char*)(uthi + atile + (size_t)c * 524288);
        const char* bh_src = (const char*)(Wthi + (c * 512 + cbase) * 32);
        #pragma unroll
        for (int it = 0; it < 2; ++it) {
            int off = (it * 4 + w) * 1024;
            gload_lds16(ah_src + off + l * 16, (char*)Ah + off);
            gload_lds16(bh_src + off + l * 16, (char*)Bh + off);
        }
        __syncthreads();

        s8v ah[4], bh[4];
        #pragma unroll
        for (int i = 0; i < 4; ++i)
            ah[i] = *reinterpret_cast<const s8v*>(&Ah[(m0 + i * 16 + lr) * 32 + koff]);
        #pragma unroll
        for (int j = 0; j < 4; ++j)
            bh[j] = *reinterpret_cast<const s8v*>(&Bh[(n0 + j * 16 + lr) * 32 + koff]);
        #pragma unroll
        for (int i = 0; i < 4; ++i)
            #pragma unroll
            for (int j = 0; j < 4; ++j)
                acc[i][j] = __builtin_amdgcn_mfma_f32_16x16x32_bf16(ah[i], bh[j], acc[i][j], 0, 0, 0);
    }

    const int quad = l >> 4;
    #pragma unroll
    for (int j = 0; j < 4; ++j) {
        int ch = cbase + n0 + j * 16 + lr;      // 256..511
        float bias = bv[ch - 256];
        #pragma unroll
        for (int i = 0; i < 4; ++i)
            #pragma unroll
            for (int r = 0; r < 4; ++r) {
                int m = m0 + i * 16 + quad * 4 + r;
                size_t pix = (size_t)(b << 14) + p0 + m;
                vbuf[pix * 256 + (ch - 256)] = (unsigned short)f2b(acc[i][j][r] + bias);
            }
    }
}

// ---------------- k_gemm2: flow = w2 @ h + b2, split bf16 (3 MFMA) -----------
__global__ __launch_bounds__(256) void k_gemm2(
    const unsigned short* __restrict__ hhi, const unsigned short* __restrict__ hlo,
    const short* __restrict__ w2thi, const short* __restrict__ w2tlo,
    const float* __restrict__ b2, float* __restrict__ flow)
{
    __shared__ __attribute__((aligned(16))) short A2h[64 * 32];
    __shared__ __attribute__((aligned(16))) short A2l[64 * 32];
    __shared__ __attribute__((aligned(16))) short B2h[128 * 32];
    __shared__ __attribute__((aligned(16))) short B2l[128 * 32];

    const int t = threadIdx.x, l = t & 63, w = t >> 6;
    const int pt = blockIdx.x * 128;
    const int b = pt >> 14, p0 = pt & 16383;

    f4v acc[8];
    #pragma unroll
    for (int j = 0; j < 8; ++j) acc[j] = (f4v){0.f, 0.f, 0.f, 0.f};

    const int lr = l & 15, koff = (l >> 4) * 8;

    for (int c = 0; c < 8; ++c) {
        __syncthreads();
        {
            int off = w * 1024;
            gload_lds16((const char*)(w2thi + c * 2048) + off + l * 16, (char*)A2h + off);
            gload_lds16((const char*)(w2tlo + c * 2048) + off + l * 16, (char*)A2l + off);
        }
        #pragma unroll
        for (int q = 0; q < 2; ++q) {
            int px = (q * 4 + w) * 16 + (l >> 2);
            const char* src_h = (const char*)hhi + ((size_t)(b << 14) + p0 + px) * 512
                                + c * 64 + (l & 3) * 16;
            const char* src_l = (const char*)hlo + ((size_t)(b << 14) + p0 + px) * 512
                                + c * 64 + (l & 3) * 16;
            int off = (q * 4 + w) * 1024;
            gload_lds16(src_h, (char*)B2h + off);
            gload_lds16(src_l, (char*)B2l + off);
        }
        __syncthreads();

        s8v a_h = *reinterpret_cast<const s8v*>(&A2h[(w * 16 + lr) * 32 + koff]);
        s8v a_l = *reinterpret_cast<const s8v*>(&A2l[(w * 16 + lr) * 32 + koff]);
        #pragma unroll
        for (int j = 0; j < 8; ++j) {
            s8v b_h = *reinterpret_cast<const s8v*>(&B2h[(j * 16 + lr) * 32 + koff]);
            s8v b_l = *reinterpret_cast<const s8v*>(&B2l[(j * 16 + lr) * 32 + koff]);
            acc[j] = __builtin_amdgcn_mfma_f32_16x16x32_bf16(a_h, b_h, acc[j], 0, 0, 0);
            acc[j] = __builtin_amdgcn_mfma_f32_16x16x32_bf16(a_h, b_l, acc[j], 0, 0, 0);
            acc[j] = __builtin_amdgcn_mfma_f32_16x16x32_bf16(a_l, b_h, acc[j], 0, 0, 0);
        }
    }

    const int quad = l >> 4;
    #pragma unroll
    for (int r = 0; r < 4; ++r) {
        int m = w * 16 + quad * 4 + r;
        float bias = b2[m];
        #pragma unroll
        for (int j = 0; j < 8; ++j)
            flow[((size_t)b * 64 + m) * HW + p0 + j * 16 + lr] = acc[j][r] + bias;
    }
}

// ---------------- k_warp: bilinear gather from bf16 pixel-major value --------
__global__ __launch_bounds__(256) void k_warp(
    const float* __restrict__ flow, const unsigned short* __restrict__ vbuf,
    float* __restrict__ out)
{
    const int g = blockIdx.x * 256 + threadIdx.x;
    const int p = g & 16383;
    const int n = g >> 14;
    const int b = n >> 5;
    const int head = n & 31;
    const int y = p >> 7;
    const int x = p & 127;

    float fx = flow[((size_t)b * 64 + 2 * head + 0) * HW + p];
    float fy = flow[((size_t)b * 64 + 2 * head + 1) * HW + p];
    float ix = (float)x + fx * 63.5f;
    float iy = (float)y + fy * 63.5f;

    float x0f = floorf(ix), y0f = floorf(iy);
    float dx = ix - x0f, dy = iy - y0f;
    int x0 = (int)x0f, y0 = (int)y0f;
    int x1 = x0 + 1,   y1 = y0 + 1;

    bool vx0 = (x0 >= 0) & (x0 < 128);
    bool vx1 = (x1 >= 0) & (x1 < 128);
    bool vy0 = (y0 >= 0) & (y0 < 128);
    bool vy1 = (y1 >= 0) & (y1 < 128);
    int x0c = min(max(x0, 0), 127), x1c = min(max(x1, 0), 127);
    int y0c = min(max(y0, 0), 127), y1c = min(max(y1, 0), 127);

    float w00 = (1.f - dx) * (1.f - dy) * ((vx0 & vy0) ? 1.f : 0.f);
    float w10 = dx * (1.f - dy)        * ((vx1 & vy0) ? 1.f : 0.f);
    float w01 = (1.f - dx) * dy        * ((vx0 & vy1) ? 1.f : 0.f);
    float w11 = dx * dy                * ((vx1 & vy1) ? 1.f : 0.f);

    const unsigned short* vb = vbuf + ((size_t)(b << 14)) * 256 + head * 8;
    s8v v00 = *reinterpret_cast<const s8v*>(vb + (size_t)(y0c * 128 + x0c) * 256);
    s8v v10 = *reinterpret_cast<const s8v*>(vb + (size_t)(y0c * 128 + x1c) * 256);
    s8v v01 = *reinterpret_cast<const s8v*>(vb + (size_t)(y1c * 128 + x0c) * 256);
    s8v v11 = *reinterpret_cast<const s8v*>(vb + (size_t)(y1c * 128 + x1c) * 256);

    float* ob = out + ((size_t)b * 256 + head * 8) * HW + p;
    #pragma unroll
    for (int ci = 0; ci < 8; ++ci) {
        float v = w00 * b2f(v00[ci]) + w10 * b2f(v10[ci])
                + w01 * b2f(v01[ci]) + w11 * b2f(v11[ci]);
        ob[(size_t)ci * HW] = v;
    }
}

extern "C" void kernel_launch(void* const* d_in, const int* in_sizes, int n_in,
                              void* d_out, int out_size, void* d_ws, size_t ws_size,
                              hipStream_t stream) {
    const float* u  = (const float*)d_in[0];
    const float* w1 = (const float*)d_in[1];
    const float* b1 = (const float*)d_in[2];
    const float* w2 = (const float*)d_in[3];
    const float* b2 = (const float*)d_in[4];
    const float* wv = (const float*)d_in[5];
    const float* bv = (const float*)d_in[6];

    char* ws = (char*)d_ws;
    // [0,32M): ut-hi, later aliased by flow (16M) after gemm1v is done
    // [32M,64M): ut-lo, later aliased by vbuf after gemm1h is done
    // [64M, 64M+448K): weight tiles
    short* uthi = (short*)ws;
    short* utlo = (short*)(ws + (32ull << 20));
    float* flow = (float*)ws;
    unsigned short* vbuf = (unsigned short*)(ws + (32ull << 20));
    short* Wthi  = (short*)(ws + (64ull << 20));   // 131072 el
    short* Wtlo  = Wthi + 131072;                  // 65536 el
    short* w2thi = Wtlo + 65536;                   // 16384 el
    short* w2tlo = w2thi + 16384;                  // 16384 el

    unsigned short* hhi = (unsigned short*)d_out;       // 32 MiB
    unsigned short* hlo = hhi + 16777216;               // 32 MiB
    float* out = (float*)d_out;

    k_prep_w<<<dim3(576),        dim3(256), 0, stream>>>(w1, wv, w2, Wthi, Wtlo, w2thi, w2tlo);
    k_prep_u<<<dim3(64, 8, 4),   dim3(256), 0, stream>>>(u, uthi, utlo);
    k_gemm1h<<<dim3(512, 2),     dim3(256), 0, stream>>>(uthi, utlo, Wthi, Wtlo, b1, hhi, hlo);
    k_gemm1v<<<dim3(512, 2),     dim3(256), 0, stream>>>(uthi, Wthi, bv, vbuf);   // vbuf over ut-lo (dead)
    k_gemm2 <<<dim3(512),        dim3(256), 0, stream>>>(hhi, hlo, w2thi, w2tlo, b2, flow); // flow over ut-hi (dead)
    k_warp  <<<dim3(8192),       dim3(256), 0, stream>>>(flow, vbuf, out);
}

// Round 4
// 217.198 us; speedup vs baseline: 1.2908x; 1.2908x over previous
//
#include <hip/hip_runtime.h>
#include <cstddef>

#define HW 16384

typedef short s8v __attribute__((ext_vector_type(8)));
typedef short s4v __attribute__((ext_vector_type(4)));
typedef float f4v __attribute__((ext_vector_type(4)));

__device__ inline short f2b(float x) {
    union { float f; unsigned u; } v; v.f = x;
    unsigned r = v.u + 0x7fff + ((v.u >> 16) & 1);
    return (short)(r >> 16);
}
__device__ inline float b2f(short h) {
    union { unsigned u; float f; } v;
    v.u = ((unsigned)(unsigned short)h) << 16;
    return v.f;
}

// ---------------- k_prep_w: weights -> chunk-tiled bf16 hi/lo ----------------
// Wthi[c][512][32] (w1 rows 0..255, wv rows 256..511); Wtlo[c][256][32] (w1 only)
// w2thi/w2tlo[c][64][32]
__global__ __launch_bounds__(256) void k_prep_w(
    const float* __restrict__ w1, const float* __restrict__ wv,
    const float* __restrict__ w2,
    short* __restrict__ Wthi, short* __restrict__ Wtlo,
    short* __restrict__ w2thi, short* __restrict__ w2tlo)
{
    int tid = blockIdx.x * 256 + threadIdx.x;   // 0..147455
    if (tid < 131072) {
        int c = tid >> 14, r = tid & 16383, ch = r >> 5, kk = r & 31;
        float f = (ch < 256) ? w1[ch * 256 + c * 32 + kk]
                             : wv[(ch - 256) * 256 + c * 32 + kk];
        short hi = f2b(f);
        Wthi[tid] = hi;
        if (ch < 256) Wtlo[(c * 256 + ch) * 32 + kk] = f2b(f - b2f(hi));
    } else {
        int o = tid - 131072;                   // 0..16383
        int c = o >> 11, r = o & 2047, dir = r >> 5, kk = r & 31;
        float f = w2[dir * 256 + c * 32 + kk];
        short hi = f2b(f);
        w2thi[o] = hi;
        w2tlo[o] = f2b(f - b2f(hi));
    }
}

// ---------------- k_mega: fused h(split) + value + flow per 64-px block ------
// Per block: 64 pixels. Waves split M: wave w handles h-ch [64w,64w+64) (split,
// 3 MFMA) and value-ch [64w,64w+64) (hi only). u transposed+converted in-kernel
// (2-stage LDS, swizzle-verified). Weights stream L2->VGPR A-frags. h stays in
// LDS; flow GEMM fused. value exits via LDS transpose -> coalesced 16B stores.
__global__ __launch_bounds__(256, 2) void k_mega(
    const float* __restrict__ u,
    const short* __restrict__ Wthi, const short* __restrict__ Wtlo,
    const short* __restrict__ w2thi, const short* __restrict__ w2tlo,
    const float* __restrict__ b1, const float* __restrict__ bv,
    const float* __restrict__ b2,
    unsigned short* __restrict__ vbuf, float* __restrict__ flow)
{
    __shared__ __attribute__((aligned(16))) char smem[69632];
    short* T1h = (short*)smem;               // 64ch x 68, 8704 B
    short* T1l = T1h + 4352;                 // ends 17408
    short* T2h = (short*)(smem + 17408);     // 64px x 72, 9216 B
    short* T2l = T2h + 4608;                 // ends 35840
    short* vt  = (short*)smem;               // 64px x 272 = 34816 B (post K-loop)
    short* hhi = (short*)smem;               // 34816 B (post value store)
    short* hlo = (short*)(smem + 34816);     // ends 69632

    const int t = threadIdx.x;
    const int l = t & 63;
    const int w = t >> 6;
    const int lr = l & 15;
    const int quad = l >> 4;
    const int quad8 = quad * 8;
    const int pt = blockIdx.x * 64;
    const int b  = pt >> 14;
    const int p0 = pt & 16383;
    const float* ub = u + (size_t)b * 256 * HW + p0;
    const int pxB = 16 * w + lr;             // stage-B pixel

    f4v acc_h[4][4], acc_v[4][4];
    #pragma unroll
    for (int i = 0; i < 4; ++i)
        #pragma unroll
        for (int j = 0; j < 4; ++j) {
            acc_h[i][j] = (f4v){0.f, 0.f, 0.f, 0.f};
            acc_v[i][j] = (f4v){0.f, 0.f, 0.f, 0.f};
        }

    // preload pair 0 (64 k-channels of u for our 64 pixels)
    float4 cur[4];
    #pragma unroll
    for (int i = 0; i < 4; ++i) {
        int idx = t + 256 * i;
        int ch = idx >> 4, px4 = (idx & 15) * 4;
        cur[i] = *reinterpret_cast<const float4*>(ub + (size_t)ch * HW + px4);
    }

    for (int pair = 0; pair < 4; ++pair) {
        // ---- stage A: convert+split into T1 [ch][px] (stride 68) ----
        #pragma unroll
        for (int i = 0; i < 4; ++i) {
            int idx = t + 256 * i;
            int ch = idx >> 4, px4 = (idx & 15) * 4;
            float4 v = cur[i];
            short h0 = f2b(v.x), h1 = f2b(v.y), h2 = f2b(v.z), h3 = f2b(v.w);
            s4v hv = {h0, h1, h2, h3};
            s4v lv = {f2b(v.x - b2f(h0)), f2b(v.y - b2f(h1)),
                      f2b(v.z - b2f(h2)), f2b(v.w - b2f(h3))};
            *reinterpret_cast<s4v*>(T1h + ch * 68 + px4) = hv;
            *reinterpret_cast<s4v*>(T1l + ch * 68 + px4) = lv;
        }
        __syncthreads();
        // ---- stage B: transpose T1 -> T2 [px][k] (stride 72) ----
        #pragma unroll
        for (int part = 0; part < 2; ++part) {
            const short* src = part ? T1l : T1h;
            short* dst = part ? T2l : T2h;
            #pragma unroll
            for (int j = 0; j < 4; ++j) {
                int k4 = (l >> 4) + 4 * j;
                s4v v = { src[(4 * k4 + 0) * 68 + pxB],
                          src[(4 * k4 + 1) * 68 + pxB],
                          src[(4 * k4 + 2) * 68 + pxB],
                          src[(4 * k4 + 3) * 68 + pxB] };
                *reinterpret_cast<s4v*>(dst + pxB * 72 + 4 * k4) = v;
            }
        }
        __syncthreads();
        // prefetch next pair (overlaps MFMA)
        if (pair < 3) {
            #pragma unroll
            for (int i = 0; i < 4; ++i) {
                int idx = t + 256 * i;
                int ch = idx >> 4, px4 = (idx & 15) * 4;
                cur[i] = *reinterpret_cast<const float4*>(
                    ub + (size_t)((pair + 1) * 64 + ch) * HW + px4);
            }
        }
        // ---- MFMA: 2 k32-steps ----
        #pragma unroll
        for (int s = 0; s < 2; ++s) {
            int c = pair * 2 + s;
            s8v bh4[4], bl4[4];
            #pragma unroll
            for (int j = 0; j < 4; ++j) {
                bh4[j] = *reinterpret_cast<const s8v*>(T2h + (16 * j + lr) * 72 + s * 32 + quad8);
                bl4[j] = *reinterpret_cast<const s8v*>(T2l + (16 * j + lr) * 72 + s * 32 + quad8);
            }
            #pragma unroll
            for (int i = 0; i < 4; ++i) {
                const size_t wb = ((size_t)c * 512 + 64 * w + 16 * i + lr) * 32 + quad8;
                s8v ahi = *reinterpret_cast<const s8v*>(Wthi + wb);
                s8v av  = *reinterpret_cast<const s8v*>(Wthi + wb + 256 * 32);
                s8v alo = *reinterpret_cast<const s8v*>(
                    Wtlo + ((size_t)c * 256 + 64 * w + 16 * i + lr) * 32 + quad8);
                #pragma unroll
                for (int j = 0; j < 4; ++j) {
                    acc_h[i][j] = __builtin_amdgcn_mfma_f32_16x16x32_bf16(ahi, bh4[j], acc_h[i][j], 0, 0, 0);
                    acc_h[i][j] = __builtin_amdgcn_mfma_f32_16x16x32_bf16(ahi, bl4[j], acc_h[i][j], 0, 0, 0);
                    acc_h[i][j] = __builtin_amdgcn_mfma_f32_16x16x32_bf16(alo, bh4[j], acc_h[i][j], 0, 0, 0);
                    acc_v[i][j] = __builtin_amdgcn_mfma_f32_16x16x32_bf16(av,  bh4[j], acc_v[i][j], 0, 0, 0);
                }
            }
        }
        __syncthreads();   // T2 reads done before next pair's T1/T2 writes
    }

    // ---- value epilogue: accs -> vt LDS -> coalesced bf16 stores ----
    #pragma unroll
    for (int i = 0; i < 4; ++i) {
        float4 bias = *reinterpret_cast<const float4*>(bv + 64 * w + 16 * i + 4 * quad);
        #pragma unroll
        for (int j = 0; j < 4; ++j) {
            int px = 16 * j + lr;
            s4v pk = { f2b(acc_v[i][j][0] + bias.x), f2b(acc_v[i][j][1] + bias.y),
                       f2b(acc_v[i][j][2] + bias.z), f2b(acc_v[i][j][3] + bias.w) };
            *reinterpret_cast<s4v*>(vt + px * 272 + 64 * w + 16 * i + 4 * quad) = pk;
        }
    }
    __syncthreads();
    {
        int px = t >> 2, ch0 = (t & 3) * 64;
        size_t pixg = (size_t)(b << 14) + p0 + px;
        #pragma unroll
        for (int e = 0; e < 8; ++e) {
            s8v vv = *reinterpret_cast<const s8v*>(vt + px * 272 + ch0 + 8 * e);
            *reinterpret_cast<s8v*>(vbuf + pixg * 256 + ch0 + 8 * e) = vv;
        }
    }
    __syncthreads();   // vt reads done before h overwrites

    // ---- h epilogue: bias+relu, split -> hhi/hlo LDS [px][272] ----
    #pragma unroll
    for (int i = 0; i < 4; ++i) {
        float4 bias = *reinterpret_cast<const float4*>(b1 + 64 * w + 16 * i + 4 * quad);
        #pragma unroll
        for (int j = 0; j < 4; ++j) {
            int px = 16 * j + lr;
            float v0 = fmaxf(acc_h[i][j][0] + bias.x, 0.f);
            float v1 = fmaxf(acc_h[i][j][1] + bias.y, 0.f);
            float v2 = fmaxf(acc_h[i][j][2] + bias.z, 0.f);
            float v3 = fmaxf(acc_h[i][j][3] + bias.w, 0.f);
            short h0 = f2b(v0), h1 = f2b(v1), h2 = f2b(v2), h3 = f2b(v3);
            s4v hv = {h0, h1, h2, h3};
            s4v lv = {f2b(v0 - b2f(h0)), f2b(v1 - b2f(h1)),
                      f2b(v2 - b2f(h2)), f2b(v3 - b2f(h3))};
            int chb = 64 * w + 16 * i + 4 * quad;
            *reinterpret_cast<s4v*>(hhi + px * 272 + chb) = hv;
            *reinterpret_cast<s4v*>(hlo + px * 272 + chb) = lv;
        }
    }
    __syncthreads();

    // ---- flow GEMM: wave w -> dirs [16w,16w+16), split bf16 (3 MFMA) ----
    f4v acc_f[4];
    #pragma unroll
    for (int j = 0; j < 4; ++j) acc_f[j] = (f4v){0.f, 0.f, 0.f, 0.f};
    #pragma unroll
    for (int c = 0; c < 8; ++c) {
        const size_t wb = ((size_t)c * 64 + 16 * w + lr) * 32 + quad8;
        s8v ahi = *reinterpret_cast<const s8v*>(w2thi + wb);
        s8v alo = *reinterpret_cast<const s8v*>(w2tlo + wb);
        #pragma unroll
        for (int j = 0; j < 4; ++j) {
            int px = 16 * j + lr;
            s8v bhh = *reinterpret_cast<const s8v*>(hhi + px * 272 + c * 32 + quad8);
            s8v bll = *reinterpret_cast<const s8v*>(hlo + px * 272 + c * 32 + quad8);
            acc_f[j] = __builtin_amdgcn_mfma_f32_16x16x32_bf16(ahi, bhh, acc_f[j], 0, 0, 0);
            acc_f[j] = __builtin_amdgcn_mfma_f32_16x16x32_bf16(ahi, bll, acc_f[j], 0, 0, 0);
            acc_f[j] = __builtin_amdgcn_mfma_f32_16x16x32_bf16(alo, bhh, acc_f[j], 0, 0, 0);
        }
    }
    float4 b2v = *reinterpret_cast<const float4*>(b2 + 16 * w + 4 * quad);
    #pragma unroll
    for (int r = 0; r < 4; ++r) {
        int dir = 16 * w + 4 * quad + r;
        float bias = (r == 0) ? b2v.x : (r == 1) ? b2v.y : (r == 2) ? b2v.z : b2v.w;
        #pragma unroll
        for (int j = 0; j < 4; ++j)
            flow[((size_t)b * 64 + dir) * HW + p0 + 16 * j + lr] = acc_f[j][r] + bias;
    }
}

// ---------------- k_warp: bilinear gather from bf16 pixel-major value --------
__global__ __launch_bounds__(256) void k_warp(
    const float* __restrict__ flow, const unsigned short* __restrict__ vbuf,
    float* __restrict__ out)
{
    const int g = blockIdx.x * 256 + threadIdx.x;
    const int p = g & 16383;
    const int n = g >> 14;
    const int b = n >> 5;
    const int head = n & 31;
    const int y = p >> 7;
    const int x = p & 127;

    float fx = flow[((size_t)b * 64 + 2 * head + 0) * HW + p];
    float fy = flow[((size_t)b * 64 + 2 * head + 1) * HW + p];
    float ix = (float)x + fx * 63.5f;
    float iy = (float)y + fy * 63.5f;

    float x0f = floorf(ix), y0f = floorf(iy);
    float dx = ix - x0f, dy = iy - y0f;
    int x0 = (int)x0f, y0 = (int)y0f;
    int x1 = x0 + 1,   y1 = y0 + 1;

    bool vx0 = (x0 >= 0) & (x0 < 128);
    bool vx1 = (x1 >= 0) & (x1 < 128);
    bool vy0 = (y0 >= 0) & (y0 < 128);
    bool vy1 = (y1 >= 0) & (y1 < 128);
    int x0c = min(max(x0, 0), 127), x1c = min(max(x1, 0), 127);
    int y0c = min(max(y0, 0), 127), y1c = min(max(y1, 0), 127);

    float w00 = (1.f - dx) * (1.f - dy) * ((vx0 & vy0) ? 1.f : 0.f);
    float w10 = dx * (1.f - dy)        * ((vx1 & vy0) ? 1.f : 0.f);
    float w01 = (1.f - dx) * dy        * ((vx0 & vy1) ? 1.f : 0.f);
    float w11 = dx * dy                * ((vx1 & vy1) ? 1.f : 0.f);

    const unsigned short* vb = vbuf + ((size_t)(b << 14)) * 256 + head * 8;
    s8v v00 = *reinterpret_cast<const s8v*>(vb + (size_t)(y0c * 128 + x0c) * 256);
    s8v v10 = *reinterpret_cast<const s8v*>(vb + (size_t)(y0c * 128 + x1c) * 256);
    s8v v01 = *reinterpret_cast<const s8v*>(vb + (size_t)(y1c * 128 + x0c) * 256);
    s8v v11 = *reinterpret_cast<const s8v*>(vb + (size_t)(y1c * 128 + x1c) * 256);

    float* ob = out + ((size_t)b * 256 + head * 8) * HW + p;
    #pragma unroll
    for (int ci = 0; ci < 8; ++ci) {
        float v = w00 * b2f(v00[ci]) + w10 * b2f(v10[ci])
                + w01 * b2f(v01[ci]) + w11 * b2f(v11[ci]);
        ob[(size_t)ci * HW] = v;
    }
}

extern "C" void kernel_launch(void* const* d_in, const int* in_sizes, int n_in,
                              void* d_out, int out_size, void* d_ws, size_t ws_size,
                              hipStream_t stream) {
    const float* u  = (const float*)d_in[0];
    const float* w1 = (const float*)d_in[1];
    const float* b1 = (const float*)d_in[2];
    const float* w2 = (const float*)d_in[3];
    const float* b2 = (const float*)d_in[4];
    const float* wv = (const float*)d_in[5];
    const float* bv = (const float*)d_in[6];

    char* ws = (char*)d_ws;
    unsigned short* vbuf = (unsigned short*)ws;                 // 33.5 MB
    float* flow  = (float*)(ws + 33554432ull);                  // 16.8 MB
    short* Wthi  = (short*)(ws + 50331648ull);                  // 131072 el
    short* Wtlo  = Wthi + 131072;                               // 65536 el
    short* w2thi = Wtlo + 65536;                                // 16384 el
    short* w2tlo = w2thi + 16384;                               // 16384 el
    float* out = (float*)d_out;

    k_prep_w<<<dim3(576),  dim3(256), 0, stream>>>(w1, wv, w2, Wthi, Wtlo, w2thi, w2tlo);
    k_mega  <<<dim3(1024), dim3(256), 0, stream>>>(u, Wthi, Wtlo, w2thi, w2tlo,
                                                   b1, bv, b2, vbuf, flow);
    k_warp  <<<dim3(8192), dim3(256), 0, stream>>>(flow, vbuf, out);
}